// Round 3
// baseline (8794.112 us; speedup 1.0000x reference)
//
#include <hip/hip_runtime.h>

#define NPTS 4096
#define FIN  64
#define FOUT 128
#define KNB  16
#define BATCH 8
#define BN_EPS 1e-5f
#define FINF 1e30f

// ---------------- ws layout (bytes) ----------------
#define OFF_SQ     (0)
#define OFF_IDX    (OFF_SQ + BATCH*NPTS*4)
#define OFF_UBAR   (OFF_IDX + BATCH*NPTS*KNB*4)
#define OFF_VT     (OFF_UBAR + BATCH*NPTS*FOUT*4)
#define OFF_GSUM   (OFF_VT + BATCH*NPTS*FOUT*4)
#define OFF_GSUMSQ (OFF_GSUM + FOUT*4)
#define OFF_AC     (OFF_GSUMSQ + FOUT*4)
// total ~= 35.8 MB

// ---------------- fused: sq = sum_f x^2 ; Ubar = (W1-W2)x + b ; Vt = W2 x ----------------
// 512 blocks x 256 thr; block covers 64 points; wave w computes o in [w*32, w*32+32).
__global__ __launch_bounds__(256) void uvsq_kernel(const float* __restrict__ x, const float* __restrict__ W,
                                                   const float* __restrict__ bias,
                                                   float* __restrict__ ubar, float* __restrict__ vt,
                                                   float* __restrict__ sqout){
  const int t = threadIdx.x, l = t & 63;
  const int w = __builtin_amdgcn_readfirstlane(t >> 6);   // wave-uniform -> W via s_load
  const int bid = blockIdx.x;
  const int b = bid & 7, grp = bid >> 3;                  // batch -> XCD round-robin
  const int n = grp*64 + l;
  const float* xp = x + (size_t)b*FIN*NPTS + n;
  float xc[FIN];
  float s = 0.f;
  #pragma unroll
  for (int f=0; f<FIN; ++f){ xc[f] = xp[(size_t)f*NPTS]; s = fmaf(xc[f], xc[f], s); }
  const size_t bn = (size_t)b*NPTS + n;
  if (w == 0) sqout[bn] = s;
  float* up = ubar + bn*FOUT;
  float* vp = vt   + bn*FOUT;
  for (int o = w*32; o < w*32+32; ++o){
    const float* wr = W + o*2*FIN;
    float a1=0.f, a2=0.f;
    #pragma unroll
    for (int f=0; f<FIN; ++f){ a1 = fmaf(wr[f], xc[f], a1); a2 = fmaf(wr[FIN+f], xc[f], a2); }
    up[o] = a1 - a2 + bias[o];
    vp[o] = a2;
  }
}

// ---------------- fused distances + top-16, full 4096 candidate sweep ----------------
// 512 blocks (= exactly 2/CU resident, one round) x 256 thr = 4 waves; 64 rows/block.
// Compute lane (cl=l&7, rl=l>>3): 2 rows x 8 cands register tile; rows' K=64 slices in
// VGPRs (rfv). xt swizzle f ^ 4*((c>>3)^(c&7)) + per-lane f-order j -> f4=(j^cl) makes
// every inner ds_read address = base(cl) + compile-time immediate, conflict-free.
// dtile aliases rowbuf (dead after rf preload); dtile swizzle col ^ 4*rl.
__global__ __launch_bounds__(256,2) void knn_kernel(const float* __restrict__ x, const float* __restrict__ sq,
                                                    int* __restrict__ idxout){
  __shared__ float xt[64*64];
  __shared__ float rowbuf[64*68];     // phase 1: [row][f] stride 68; phase 2: dtile [row*64 + swz(col)]
  __shared__ float rowsq[64];
  const int t = threadIdx.x;
  const int w = t >> 6;
  const int l = t & 63;
  const int b  = blockIdx.x & 7;      // batch -> XCD (x[b] = 1MB, L2-resident)
  const int n0 = (blockIdx.x >> 3) * 64;
  const float* xb  = x  + (size_t)b*FIN*NPTS;
  const float* sqb = sq + b*NPTS;

  // stage the 64 rows' features + rowsq
  for (int j=t; j<4096; j+=256){ int row = j & 63, f = j >> 6; rowbuf[row*68+f] = xb[(size_t)f*NPTS + n0 + row]; }
  if (t < 64) rowsq[t] = sqb[n0 + t];
  __syncthreads();

  const int cl = l & 7;
  const int rl = l >> 3;
  const int row0 = w*16 + rl*2;

  // rf registers, stored in per-lane reordered f-slice order: rfv[r][j] = row f-slice (j^cl)
  float4 rfv[2][16];
  #pragma unroll
  for (int r=0;r<2;++r){
    #pragma unroll
    for (int j=0;j<16;++j) rfv[r][j] = *(const float4*)&rowbuf[(row0+r)*68 + 4*(j^cl)];
  }
  const float rsq0 = rowsq[row0], rsq1 = rowsq[row0+1];

  // selection state (sorted ascending)
  float val[16]; int idx[16];
  #pragma unroll
  for (int q=0;q<16;++q){ val[q] = FINF; idx[q] = 0; }
  const int selq = l >> 2;                       // 0..15: row within wave's 16
  const int selrow = w*16 + selq;
  const int selc = l & 3;
  const int selswz = 4*((selq>>1)&7);
  const int sbase = selrow*64;

  // staging constants: thread owns candidate group c4 (4 cands), f = it*16 + (t>>4)
  const int c4 = (t & 15) << 2;
  const int tf = t >> 4;
  int sw0, sw1, sw2, sw3;
  { int c;
    c = c4+0; sw0 = 4*((c>>3) ^ (c&7));
    c = c4+1; sw1 = 4*((c>>3) ^ (c&7));
    c = c4+2; sw2 = 4*((c>>3) ^ (c&7));
    c = c4+3; sw3 = 4*((c>>3) ^ (c&7)); }

  // prefetch chunk 0
  float4 pre[4];
  #pragma unroll
  for (int it=0; it<4; ++it) pre[it] = *(const float4*)(xb + (size_t)(it*16 + tf)*NPTS + c4);
  float4 pca = *(const float4*)&sqb[cl*8];
  float4 pcb = *(const float4*)&sqb[cl*8 + 4];

  const float* xtl = xt + cl*512;                // lane-constant base for inner reads

  for (int c0=0; c0<NPTS; c0+=64){
    __syncthreads();                             // all waves done reading xt of prev chunk
    #pragma unroll
    for (int it=0; it<4; ++it){
      const int f = it*16 + tf;
      const float4 v = pre[it];
      xt[(c4+0)*64 + (f ^ sw0)] = v.x;
      xt[(c4+1)*64 + (f ^ sw1)] = v.y;
      xt[(c4+2)*64 + (f ^ sw2)] = v.z;
      xt[(c4+3)*64 + (f ^ sw3)] = v.w;
    }
    const float4 ca = pca, cb = pcb;
    { // prefetch next chunk while this one computes (T14)
      const int cn = (c0 + 64 < NPTS) ? c0 + 64 : 0;
      #pragma unroll
      for (int it=0; it<4; ++it) pre[it] = *(const float4*)(xb + (size_t)(it*16 + tf)*NPTS + cn + c4);
      pca = *(const float4*)&sqb[cn + cl*8];
      pcb = *(const float4*)&sqb[cn + cl*8 + 4];
    }
    __syncthreads();                             // xt ready

    float acc[8][2];
    #pragma unroll
    for (int k=0;k<8;++k){ acc[k][0]=0.f; acc[k][1]=0.f; }
    #pragma unroll
    for (int j=0;j<16;++j){
      #pragma unroll
      for (int k=0;k<8;++k){
        const float4 xv = *(const float4*)&xtl[k*64 + 4*(j^k)];   // imm-offset ds_read_b128
        const float4 ra = rfv[0][j], rb = rfv[1][j];
        acc[k][0] = fmaf(xv.x, ra.x, acc[k][0]);
        acc[k][0] = fmaf(xv.y, ra.y, acc[k][0]);
        acc[k][0] = fmaf(xv.z, ra.z, acc[k][0]);
        acc[k][0] = fmaf(xv.w, ra.w, acc[k][0]);
        acc[k][1] = fmaf(xv.x, rb.x, acc[k][1]);
        acc[k][1] = fmaf(xv.y, rb.y, acc[k][1]);
        acc[k][1] = fmaf(xv.z, rb.z, acc[k][1]);
        acc[k][1] = fmaf(xv.w, rb.w, acc[k][1]);
      }
    }

    // d = rsq + csq - 2*dot ; self-exclusion only in the diagonal chunk
    float d0[8], d1[8];
    #pragma unroll
    for (int k=0;k<8;++k){
      const float cs = (k<4) ? ((k==0)?ca.x:(k==1)?ca.y:(k==2)?ca.z:ca.w)
                             : ((k==4)?cb.x:(k==5)?cb.y:(k==6)?cb.z:cb.w);
      d0[k] = fmaf(-2.f, acc[k][0], rsq0 + cs);
      d1[k] = fmaf(-2.f, acc[k][1], rsq1 + cs);
    }
    if (c0 == n0){
      #pragma unroll
      for (int k=0;k<8;++k){
        if (row0   == cl*8 + k) d0[k] = FINF;
        if (row0+1 == cl*8 + k) d1[k] = FINF;
      }
    }
    { // dtile write: rowbuf[row*64 + ((8cl+4h) ^ 4rl)], exactly bank-floor
      const int swr = 4*rl;
      *(float4*)&rowbuf[ row0   *64 + ((8*cl+0) ^ swr)] = make_float4(d0[0],d0[1],d0[2],d0[3]);
      *(float4*)&rowbuf[ row0   *64 + ((8*cl+4) ^ swr)] = make_float4(d0[4],d0[5],d0[6],d0[7]);
      *(float4*)&rowbuf[(row0+1)*64 + ((8*cl+0) ^ swr)] = make_float4(d1[0],d1[1],d1[2],d1[3]);
      *(float4*)&rowbuf[(row0+1)*64 + ((8*cl+4) ^ swr)] = make_float4(d1[4],d1[5],d1[6],d1[7]);
    }
    // two-phase selection (intra-wave LDS; in-order LDS pipe + compiler deps)
    {
      const float thr = val[15];
      unsigned mask = 0;
      #pragma unroll
      for (int j=15;j>=0;--j){
        const float d = rowbuf[sbase + (selc + ((4*j) ^ selswz))];
        mask = (mask << 1) | (d < thr ? 1u : 0u);
      }
      while (mask){
        const int j = __builtin_ctz(mask);
        mask &= mask - 1;
        const float d = rowbuf[sbase + (selc + ((4*j) ^ selswz))];
        if (d < val[15]){
          val[15] = d; idx[15] = c0 + selc + 4*j;
          #pragma unroll
          for (int q=15;q>0;--q){
            const bool s_ = val[q] < val[q-1];
            const float tv = val[q], tu = val[q-1];
            val[q]   = s_ ? tu : tv;
            val[q-1] = s_ ? tv : tu;
            const int iv = idx[q], iu = idx[q-1];
            idx[q]   = s_ ? iu : iv;
            idx[q-1] = s_ ? iv : iu;
          }
        }
      }
    }
  }

  // merge 4 sorted per-lane lists -> final top-16 per row, write indices
  int myidx[4];
  #pragma unroll
  for (int round=0; round<16; ++round){
    float v = val[0]; int ii = idx[0]; int src = selc;
    #pragma unroll
    for (int mm=1; mm<4; mm<<=1){
      const float ov = __shfl_xor(v, mm);
      const int   oi = __shfl_xor(ii, mm);
      const int   os = __shfl_xor(src, mm);
      const bool take = (ov < v) || (ov == v && os < src);
      v = take ? ov : v; ii = take ? oi : ii; src = take ? os : src;
    }
    if (selc == src){
      #pragma unroll
      for (int q=0;q<15;++q){ val[q]=val[q+1]; idx[q]=idx[q+1]; }
      val[15] = FINF;
    }
    if ((round & 3) == selc) myidx[round>>2] = ii;
  }
  {
    const int bn = b*NPTS + n0 + selrow;
    int* op = idxout + (size_t)bn*KNB;
    #pragma unroll
    for (int q=0;q<4;++q) op[q*4 + selc] = myidx[q];
  }
}

// ---------------- gather V at neighbors: sel=Ubar+(gamma>=0?max:min), channel stats ----------------
// 512 blocks x 256 thr; thread (o=t&127, h=t>>7) owns 8 groups of 4 consecutive points ->
// float4 output stores; all 16 neighbors per point; atomics once per thread.
__global__ __launch_bounds__(256) void gather_kernel(const float* __restrict__ vt, const float* __restrict__ ubar,
                                                     const int* __restrict__ idxnb, const float* __restrict__ gamma,
                                                     float* __restrict__ outsel, float* __restrict__ gsum,
                                                     float* __restrict__ gsumsq){
  const int t = threadIdx.x;
  const int o = t & 127;
  const int h = __builtin_amdgcn_readfirstlane(t >> 7);   // wave-uniform point half
  const int b = blockIdx.x & 7;                           // batch -> XCD: vt[b]=2MB L2-resident
  const int nblk = (blockIdx.x >> 3) * 64;
  const float gam = gamma[o];
  const float* vtb = vt + (size_t)b*NPTS*FOUT + o;
  float bs = 0.f, bsq = 0.f;
  for (int p=0; p<8; ++p){
    const int ng = nblk + (h*8 + p)*4;
    float selv[4];
    #pragma unroll
    for (int j=0; j<4; ++j){
      const int n  = ng + j;
      const int bn = b*NPTS + n;
      const int* ip = idxnb + (size_t)bn*KNB;             // wave-uniform -> s_load
      float mx = -FINF, mn = FINF, s1 = 0.f, s2 = 0.f;
      #pragma unroll
      for (int kk=0; kk<KNB; ++kk){
        const int m = ip[kk];
        const float v = vtb[(size_t)m*FOUT];              // 256B coalesced per neighbor
        mx = fmaxf(mx, v); mn = fminf(mn, v); s1 += v; s2 = fmaf(v, v, s2);
      }
      const float c = ubar[(size_t)bn*FOUT + o];
      selv[j] = c + (gam >= 0.f ? mx : mn);
      bs  += fmaf(16.f, c, s1);                           // sum_k y = 16c + S1
      bsq += fmaf(16.f*c, c, fmaf(2.f*c, s1, s2));        // sum_k y^2 = 16c^2 + 2c S1 + S2
    }
    *(float4*)&outsel[((size_t)b*FOUT + o)*NPTS + ng] = make_float4(selv[0],selv[1],selv[2],selv[3]);
  }
  atomicAdd(&gsum[o], bs);
  atomicAdd(&gsumsq[o], bsq);
}

// ---------------- BN stats -> per-channel affine a,c ----------------
__global__ void stats_kernel(const float* __restrict__ gsum, const float* __restrict__ gsumsq,
                             const float* __restrict__ gamma, const float* __restrict__ beta,
                             float* __restrict__ ac){
  const int o = threadIdx.x;
  const float invM = 1.f / (float)(BATCH*NPTS*KNB);
  const float mean = gsum[o] * invM;
  const float var  = gsumsq[o] * invM - mean*mean;
  const float r = rsqrtf(var + BN_EPS);
  const float a = gamma[o] * r;
  ac[o] = a;
  ac[FOUT+o] = beta[o] - mean * a;
}

// ---------------- in-place relu(a*y+c) on d_out ----------------
__global__ __launch_bounds__(256) void apply_kernel(float* __restrict__ out, const float* __restrict__ ac){
  const int i4 = blockIdx.x*256 + threadIdx.x;
  const int o = (i4 >> 10) & 127;
  const float a = ac[o], c = ac[FOUT+o];
  float4* p = (float4*)out;
  float4 v = p[i4];
  v.x = fmaxf(fmaf(a, v.x, c), 0.f);
  v.y = fmaxf(fmaf(a, v.y, c), 0.f);
  v.z = fmaxf(fmaf(a, v.z, c), 0.f);
  v.w = fmaxf(fmaf(a, v.w, c), 0.f);
  p[i4] = v;
}

extern "C" void kernel_launch(void* const* d_in, const int* in_sizes, int n_in,
                              void* d_out, int out_size, void* d_ws, size_t ws_size,
                              hipStream_t stream){
  const float* x     = (const float*)d_in[0];
  const float* W     = (const float*)d_in[1];
  const float* bias  = (const float*)d_in[2];
  const float* gamma = (const float*)d_in[3];
  const float* beta  = (const float*)d_in[4];
  char* ws = (char*)d_ws;
  float* sq     = (float*)(ws + OFF_SQ);
  int*   idxnb  = (int*)(ws + OFF_IDX);
  float* ubar   = (float*)(ws + OFF_UBAR);
  float* vt     = (float*)(ws + OFF_VT);
  float* gsum   = (float*)(ws + OFF_GSUM);
  float* gsumsq = (float*)(ws + OFF_GSUMSQ);
  float* ac     = (float*)(ws + OFF_AC);
  float* out    = (float*)d_out;

  hipMemsetAsync(ws + OFF_GSUM, 0, 2*FOUT*4, stream);
  uvsq_kernel  <<<BATCH*NPTS/64, 256, 0, stream>>>(x, W, bias, ubar, vt, sq);
  knn_kernel   <<<BATCH*NPTS/64, 256, 0, stream>>>(x, sq, idxnb);
  gather_kernel<<<BATCH*NPTS/64, 256, 0, stream>>>(vt, ubar, idxnb, gamma, out, gsum, gsumsq);
  stats_kernel <<<1, FOUT, 0, stream>>>(gsum, gsumsq, gamma, beta, ac);
  apply_kernel <<<BATCH*FOUT*NPTS/1024, 256, 0, stream>>>(out, ac);
}

// Round 4
// 1108.038 us; speedup vs baseline: 7.9367x; 7.9367x over previous
//
#include <hip/hip_runtime.h>

#define NPTS 4096
#define FIN  64
#define FOUT 128
#define KNB  16
#define BATCH 8
#define BN_EPS 1e-5f
#define FINF 1e30f

// ---------------- ws layout (bytes) ----------------
#define OFF_SQ     (0)
#define OFF_IDX    (OFF_SQ + BATCH*NPTS*4)
#define OFF_PAIRS  (OFF_IDX + BATCH*NPTS*KNB*4)
#define OFF_UBAR   (OFF_PAIRS + BATCH*NPTS*32*8)
#define OFF_VT     (OFF_UBAR + BATCH*NPTS*FOUT*4)
#define OFF_GSUM   (OFF_VT + BATCH*NPTS*FOUT*4)
#define OFF_GSUMSQ (OFF_GSUM + FOUT*4)
#define OFF_AC     (OFF_GSUMSQ + FOUT*4)

// ---------------- fused: sq = sum_f x^2 ; Ubar = (W1-W2)x + b ; Vt = W2 x ----------------
__global__ __launch_bounds__(256) void uvsq_kernel(const float* __restrict__ x, const float* __restrict__ W,
                                                   const float* __restrict__ bias,
                                                   float* __restrict__ ubar, float* __restrict__ vt,
                                                   float* __restrict__ sqout){
  const int t = threadIdx.x, l = t & 63;
  const int w = __builtin_amdgcn_readfirstlane(t >> 6);   // wave-uniform -> W via s_load
  const int bid = blockIdx.x;
  const int b = bid & 7, grp = bid >> 3;                  // batch -> XCD round-robin
  const int n = grp*64 + l;
  const float* xp = x + (size_t)b*FIN*NPTS + n;
  float xc[FIN];
  float s = 0.f;
  #pragma unroll
  for (int f=0; f<FIN; ++f){ xc[f] = xp[(size_t)f*NPTS]; s = fmaf(xc[f], xc[f], s); }
  const size_t bn = (size_t)b*NPTS + n;
  if (w == 0) sqout[bn] = s;
  float* up = ubar + bn*FOUT;
  float* vp = vt   + bn*FOUT;
  for (int o = w*32; o < w*32+32; ++o){
    const float* wr = W + o*2*FIN;
    float a1=0.f, a2=0.f;
    #pragma unroll
    for (int f=0; f<FIN; ++f){ a1 = fmaf(wr[f], xc[f], a1); a2 = fmaf(wr[FIN+f], xc[f], a2); }
    up[o] = a1 - a2 + bias[o];
    vp[o] = a2;
  }
}

// ---------------- fused distances + top-16 (half candidate range per block) ----------------
// Round-2 proven structure + 3 fixes:
//  (a) dtile aliased into xt (3rd barrier per chunk) -> LDS 33.9KB -> 4 blocks/CU, grid 1024 = 1 round
//  (b) launch_bounds(256,4): VGPR <= 128, row features stay in LDS (r3 spill lesson)
//  (c) 16 chunk-invariant per-i xv byte offsets; jc folded into ds immediate
// compute lane: (cl=l&15 -> 4 cands, rl=l>>4 -> 4 rows) 4x4 register tile, K=64 via LDS.
// dtile phys: row*64 + ((4*(c>>2)) ^ 8*((row>>2)&3) ^ 4*(row&3)) + (c&3)  [writes=b128 floor, reads 2-way]
__global__ __launch_bounds__(256,4) void knn_kernel(const float* __restrict__ x, const float* __restrict__ sq,
                                                    float2* __restrict__ pairs){
  __shared__ float xt[64*64];     // phase A: swizzled cand features; phase B: dtile (aliased)
  __shared__ float rowf[64*68];   // [row][f] stride 68 (rf broadcast reads 2-way = free)
  __shared__ float rowsq[64];
  const int t = threadIdx.x;
  const int w = t >> 6;
  const int l = t & 63;
  const int bid = blockIdx.x;
  const int b = bid & 7;                 // batch -> XCD (x[b] = 1MB L2-resident)
  const int rest = bid >> 3;
  const int z = rest & 1;                // candidate half
  const int n0 = (rest >> 1) * 64;
  const int cbase = z * 2048;
  const float* xb  = x  + (size_t)b*FIN*NPTS;
  const float* sqb = sq + b*NPTS;

  for (int j=t; j<4096; j+=256){ int row = j & 63, f = j >> 6; rowf[row*68+f] = xb[(size_t)f*NPTS + n0 + row]; }
  if (t < 64) rowsq[t] = sqb[n0 + t];
  __syncthreads();

  const int cl = l & 15;
  const int rl = l >> 4;
  float rsq[4]; int nself[4];
  #pragma unroll
  for (int jr=0;jr<4;++jr){ int r = w*16 + rl*4 + jr; rsq[jr] = rowsq[r]; nself[jr] = n0 + r; }

  float val[16]; int idx[16];
  #pragma unroll
  for (int q=0;q<16;++q){ val[q] = FINF; idx[q] = 0; }
  const int selrow = w*16 + (l>>2);
  const int selc   = l & 3;
  const int Xs     = (8*((l>>4)&3)) ^ (4*((l>>2)&3));   // dtile row-XOR for sel lane
  const int sbase  = selrow*64 + selc;

  // (c) chunk-invariant xv byte offsets: addr = xt + off[i] + jc*256
  int off[16];
  #pragma unroll
  for (int i=0;i<16;++i) off[i] = cl*1024 + 16*(i^cl);

  for (int cc=0; cc<2048; cc+=64){
    const int c0 = cbase + cc;
    __syncthreads();                           // everyone done selecting from xt(dtile) of prev chunk
    #pragma unroll
    for (int it=0; it<4; ++it){                // stage 64f x 64c, pre-swizzled (r2 verbatim)
      int i4 = it*256 + t;
      int f  = i4 >> 4;
      int c4 = (i4 & 15) << 2;
      float4 v = *(const float4*)(xb + (size_t)f*NPTS + c0 + c4);
      int fp = f ^ c4;
      xt[(c4+0)*64 + fp] = v.x;
      xt[(c4+1)*64 + fp] = v.y;
      xt[(c4+2)*64 + fp] = v.z;
      xt[(c4+3)*64 + fp] = v.w;
    }
    float csq[4];
    #pragma unroll
    for (int jc=0;jc<4;++jc) csq[jc] = sqb[c0 + cl*4 + jc];
    __syncthreads();                           // xt ready

    float acc[4][4];
    #pragma unroll
    for (int jc=0;jc<4;++jc){
      #pragma unroll
      for (int jr=0;jr<4;++jr) acc[jc][jr]=0.f;
    }
    #pragma unroll
    for (int i=0;i<16;++i){
      float4 xv[4], rf[4];
      #pragma unroll
      for (int jc=0;jc<4;++jc) xv[jc] = *(const float4*)((const char*)xt + off[i] + jc*256);
      #pragma unroll
      for (int jr=0;jr<4;++jr) rf[jr] = *(const float4*)&rowf[(w*16+rl*4+jr)*68 + i*4];
      #pragma unroll
      for (int jc=0;jc<4;++jc){
        #pragma unroll
        for (int jr=0;jr<4;++jr){
          acc[jc][jr] = fmaf(xv[jc].x, rf[jr].x, acc[jc][jr]);
          acc[jc][jr] = fmaf(xv[jc].y, rf[jr].y, acc[jc][jr]);
          acc[jc][jr] = fmaf(xv[jc].z, rf[jr].z, acc[jc][jr]);
          acc[jc][jr] = fmaf(xv[jc].w, rf[jr].w, acc[jc][jr]);
        }
      }
    }

    // d = rsq + csq - 2*dot into registers (before barrier), self-exclusion per element
    float4 dres[4];
    #pragma unroll
    for (int jr=0;jr<4;++jr){
      const int c = c0 + cl*4;
      float4 dd;
      dd.x = fmaf(-2.f, acc[0][jr], rsq[jr] + csq[0]); if (c+0 == nself[jr]) dd.x = FINF;
      dd.y = fmaf(-2.f, acc[1][jr], rsq[jr] + csq[1]); if (c+1 == nself[jr]) dd.y = FINF;
      dd.z = fmaf(-2.f, acc[2][jr], rsq[jr] + csq[2]); if (c+2 == nself[jr]) dd.z = FINF;
      dd.w = fmaf(-2.f, acc[3][jr], rsq[jr] + csq[3]); if (c+3 == nself[jr]) dd.w = FINF;
      dres[jr] = dd;
    }
    __syncthreads();                           // all waves done reading xt -> safe to overwrite as dtile
    #pragma unroll
    for (int jr=0;jr<4;++jr){                  // b128 dtile write, phys col = 4cl ^ (8rl ^ 4jr)
      const int row = w*16 + rl*4 + jr;
      const int X   = (8*rl) ^ (4*jr);
      *(float4*)&xt[row*64 + ((cl*4) ^ X)] = dres[jr];
    }
    // two-phase selection (wave-local rows; LDS deps handled by compiler lgkmcnt)
    {
      const float thr = val[15];
      unsigned mask = 0;
      #pragma unroll
      for (int j=15;j>=0;--j){
        const float d = xt[sbase + ((4*j) ^ Xs)];
        mask = (mask << 1) | (d < thr ? 1u : 0u);
      }
      while (mask){
        const int j = __builtin_ctz(mask);
        mask &= mask - 1;
        const float d = xt[sbase + ((4*j) ^ Xs)];
        if (d < val[15]){
          val[15] = d; idx[15] = c0 + selc + 4*j;
          #pragma unroll
          for (int q=15;q>0;--q){
            const bool s_ = val[q] < val[q-1];
            const float tv = val[q], tu = val[q-1];
            val[q]   = s_ ? tu : tv;
            val[q-1] = s_ ? tv : tu;
            const int iv = idx[q], iu = idx[q-1];
            idx[q]   = s_ ? iu : iv;
            idx[q-1] = s_ ? iv : iu;
          }
        }
      }
    }
  }

  // merge 4 sorted per-lane lists -> sorted global top-16 of this half
  float myv[4]; int myi[4];
  #pragma unroll
  for (int round=0; round<16; ++round){
    float v = val[0]; int ii = idx[0]; int src = selc;
    #pragma unroll
    for (int mm=1; mm<4; mm<<=1){
      const float ov = __shfl_xor(v, mm);
      const int   oi = __shfl_xor(ii, mm);
      const int   os = __shfl_xor(src, mm);
      const bool take = (ov < v) || (ov == v && os < src);
      v = take ? ov : v; ii = take ? oi : ii; src = take ? os : src;
    }
    if (selc == src){
      #pragma unroll
      for (int q=0;q<15;++q){ val[q]=val[q+1]; idx[q]=idx[q+1]; }
      val[15] = FINF;
    }
    if ((round & 3) == selc){ myv[round>>2] = v; myi[round>>2] = ii; }
  }
  {
    const int bn = b*NPTS + n0 + selrow;
    float2* pp = pairs + (size_t)bn*32 + z*16;
    #pragma unroll
    for (int q=0;q<4;++q) pp[q*4 + selc] = make_float2(myv[q], __int_as_float(myi[q]));
  }
}

// ---------------- merge two sorted 16-lists per row -> final 16 neighbor indices ----------------
__global__ __launch_bounds__(256) void kmerge_kernel(const float2* __restrict__ pairs, int* __restrict__ idxout){
  const int bn = blockIdx.x*256 + threadIdx.x;
  const float2* p = pairs + (size_t)bn*32;
  float val[16]; int idx[16];
  #pragma unroll
  for (int q=0;q<16;++q){ float2 e = p[q]; val[q] = e.x; idx[q] = __float_as_int(e.y); }
  #pragma unroll
  for (int j=16;j<32;++j){
    float2 e = p[j];
    if (e.x < val[15]){
      val[15] = e.x; idx[15] = __float_as_int(e.y);
      #pragma unroll
      for (int q=15;q>0;--q){
        const bool s_ = val[q] < val[q-1];
        const float tv = val[q], tu = val[q-1];
        val[q] = s_?tu:tv; val[q-1] = s_?tv:tu;
        const int iv = idx[q], iu = idx[q-1];
        idx[q] = s_?iu:iv; idx[q-1] = s_?iv:iu;
      }
    }
  }
  int* op = idxout + (size_t)bn*KNB;
  #pragma unroll
  for (int q=0;q<KNB;++q) op[q] = idx[q];
}

// ---------------- gather V at neighbors: sel=Ubar+(gamma>=0?max:min), channel stats ----------------
__global__ __launch_bounds__(256) void gather_kernel(const float* __restrict__ vt, const float* __restrict__ ubar,
                                                     const int* __restrict__ idxnb, const float* __restrict__ gamma,
                                                     float* __restrict__ outsel, float* __restrict__ gsum,
                                                     float* __restrict__ gsumsq){
  const int t = threadIdx.x;
  const int o = t & 127;
  const int h = __builtin_amdgcn_readfirstlane(t >> 7);   // wave-uniform point half
  const int b = blockIdx.x & 7;                           // batch -> XCD: vt[b]=2MB L2-resident
  const int nblk = (blockIdx.x >> 3) * 64;
  const float gam = gamma[o];
  const float* vtb = vt + (size_t)b*NPTS*FOUT + o;
  float bs = 0.f, bsq = 0.f;
  for (int p=0; p<8; ++p){
    const int ng = nblk + (h*8 + p)*4;
    float selv[4];
    #pragma unroll
    for (int j=0; j<4; ++j){
      const int n  = ng + j;
      const int bn = b*NPTS + n;
      const int* ip = idxnb + (size_t)bn*KNB;             // wave-uniform -> s_load
      float mx = -FINF, mn = FINF, s1 = 0.f, s2 = 0.f;
      #pragma unroll
      for (int kk=0; kk<KNB; ++kk){
        const int m = ip[kk];
        const float v = vtb[(size_t)m*FOUT];              // 256B coalesced per neighbor
        mx = fmaxf(mx, v); mn = fminf(mn, v); s1 += v; s2 = fmaf(v, v, s2);
      }
      const float c = ubar[(size_t)bn*FOUT + o];
      selv[j] = c + (gam >= 0.f ? mx : mn);
      bs  += fmaf(16.f, c, s1);                           // sum_k y = 16c + S1
      bsq += fmaf(16.f*c, c, fmaf(2.f*c, s1, s2));        // sum_k y^2 = 16c^2 + 2c S1 + S2
    }
    *(float4*)&outsel[((size_t)b*FOUT + o)*NPTS + ng] = make_float4(selv[0],selv[1],selv[2],selv[3]);
  }
  atomicAdd(&gsum[o], bs);
  atomicAdd(&gsumsq[o], bsq);
}

// ---------------- BN stats -> per-channel affine a,c ----------------
__global__ void stats_kernel(const float* __restrict__ gsum, const float* __restrict__ gsumsq,
                             const float* __restrict__ gamma, const float* __restrict__ beta,
                             float* __restrict__ ac){
  const int o = threadIdx.x;
  const float invM = 1.f / (float)(BATCH*NPTS*KNB);
  const float mean = gsum[o] * invM;
  const float var  = gsumsq[o] * invM - mean*mean;
  const float r = rsqrtf(var + BN_EPS);
  const float a = gamma[o] * r;
  ac[o] = a;
  ac[FOUT+o] = beta[o] - mean * a;
}

// ---------------- in-place relu(a*y+c) on d_out ----------------
__global__ __launch_bounds__(256) void apply_kernel(float* __restrict__ out, const float* __restrict__ ac){
  const int i4 = blockIdx.x*256 + threadIdx.x;
  const int o = (i4 >> 10) & 127;
  const float a = ac[o], c = ac[FOUT+o];
  float4* p = (float4*)out;
  float4 v = p[i4];
  v.x = fmaxf(fmaf(a, v.x, c), 0.f);
  v.y = fmaxf(fmaf(a, v.y, c), 0.f);
  v.z = fmaxf(fmaf(a, v.z, c), 0.f);
  v.w = fmaxf(fmaf(a, v.w, c), 0.f);
  p[i4] = v;
}

extern "C" void kernel_launch(void* const* d_in, const int* in_sizes, int n_in,
                              void* d_out, int out_size, void* d_ws, size_t ws_size,
                              hipStream_t stream){
  const float* x     = (const float*)d_in[0];
  const float* W     = (const float*)d_in[1];
  const float* bias  = (const float*)d_in[2];
  const float* gamma = (const float*)d_in[3];
  const float* beta  = (const float*)d_in[4];
  char* ws = (char*)d_ws;
  float*  sq     = (float*)(ws + OFF_SQ);
  int*    idxnb  = (int*)(ws + OFF_IDX);
  float2* pairs  = (float2*)(ws + OFF_PAIRS);
  float*  ubar   = (float*)(ws + OFF_UBAR);
  float*  vt     = (float*)(ws + OFF_VT);
  float*  gsum   = (float*)(ws + OFF_GSUM);
  float*  gsumsq = (float*)(ws + OFF_GSUMSQ);
  float*  ac     = (float*)(ws + OFF_AC);
  float*  out    = (float*)d_out;

  hipMemsetAsync(ws + OFF_GSUM, 0, 2*FOUT*4, stream);
  uvsq_kernel  <<<BATCH*NPTS/64, 256, 0, stream>>>(x, W, bias, ubar, vt, sq);
  knn_kernel   <<<BATCH*(NPTS/64)*2, 256, 0, stream>>>(x, sq, pairs);
  kmerge_kernel<<<BATCH*NPTS/256, 256, 0, stream>>>(pairs, idxnb);
  gather_kernel<<<BATCH*(NPTS/64), 256, 0, stream>>>(vt, ubar, idxnb, gamma, out, gsum, gsumsq);
  stats_kernel <<<1, FOUT, 0, stream>>>(gsum, gsumsq, gamma, beta, ac);
  apply_kernel <<<BATCH*FOUT*NPTS/1024, 256, 0, stream>>>(out, ac);
}

// Round 5
// 760.866 us; speedup vs baseline: 11.5580x; 1.4563x over previous
//
#include <hip/hip_runtime.h>

#define NPTS 4096
#define FIN  64
#define FOUT 128
#define KNB  16
#define BATCH 8
#define BN_EPS 1e-5f
#define FINF 1e30f

// ---------------- ws layout (bytes) ----------------
#define OFF_SQ     (0)
#define OFF_IDX    (OFF_SQ + BATCH*NPTS*4)
#define OFF_PAIRS  (OFF_IDX + BATCH*NPTS*KNB*4)
#define OFF_UBAR   (OFF_PAIRS + BATCH*NPTS*32*8)
#define OFF_VT     (OFF_UBAR + BATCH*NPTS*FOUT*4)
#define OFF_GSUM   (OFF_VT + BATCH*NPTS*FOUT*4)
#define OFF_GSUMSQ (OFF_GSUM + FOUT*4)
#define OFF_AC     (OFF_GSUMSQ + FOUT*4)

// ---------------- fused: sq = sum_f x^2 ; Ubar = (W1-W2)x + b ; Vt = W2 x ----------------
__global__ __launch_bounds__(256) void uvsq_kernel(const float* __restrict__ x, const float* __restrict__ W,
                                                   const float* __restrict__ bias,
                                                   float* __restrict__ ubar, float* __restrict__ vt,
                                                   float* __restrict__ sqout){
  const int t = threadIdx.x, l = t & 63;
  const int w = __builtin_amdgcn_readfirstlane(t >> 6);   // wave-uniform -> W via s_load
  const int bid = blockIdx.x;
  const int b = bid & 7, grp = bid >> 3;                  // batch -> XCD round-robin
  const int n = grp*64 + l;
  const float* xp = x + (size_t)b*FIN*NPTS + n;
  float xc[FIN];
  float s = 0.f;
  #pragma unroll
  for (int f=0; f<FIN; ++f){ xc[f] = xp[(size_t)f*NPTS]; s = fmaf(xc[f], xc[f], s); }
  const size_t bn = (size_t)b*NPTS + n;
  if (w == 0) sqout[bn] = s;
  float* up = ubar + bn*FOUT;
  float* vp = vt   + bn*FOUT;
  for (int o = w*32; o < w*32+32; ++o){
    const float* wr = W + o*2*FIN;
    float a1=0.f, a2=0.f;
    #pragma unroll
    for (int f=0; f<FIN; ++f){ a1 = fmaf(wr[f], xc[f], a1); a2 = fmaf(wr[FIN+f], xc[f], a2); }
    up[o] = a1 - a2 + bias[o];
    vp[o] = a2;
  }
}

// ---------------- fused distances + top-16 (half candidate range per block) ----------------
// r4 structure (dtile aliased into xt -> LDS 33.9KB -> 4 blocks/CU, grid 1024 = 1 round)
// with the register bound REVERTED to (256,3): r4's (256,4) forced a 64-VGPR target and
// spilled 2.9GB/dispatch to scratch (the whole regression). (256,3) is the proven r2 state.
__global__ __launch_bounds__(256,3) void knn_kernel(const float* __restrict__ x, const float* __restrict__ sq,
                                                    float2* __restrict__ pairs){
  __shared__ float xt[64*64];     // phase A: swizzled cand features; phase B: dtile (aliased)
  __shared__ float rowf[64*68];   // [row][f] stride 68 (rf broadcast reads 2-way = free)
  __shared__ float rowsq[64];
  const int t = threadIdx.x;
  const int w = t >> 6;
  const int l = t & 63;
  const int bid = blockIdx.x;
  const int b = bid & 7;                 // batch -> XCD (x[b] = 1MB L2-resident)
  const int rest = bid >> 3;
  const int z = rest & 1;                // candidate half
  const int n0 = (rest >> 1) * 64;
  const int cbase = z * 2048;
  const float* xb  = x  + (size_t)b*FIN*NPTS;
  const float* sqb = sq + b*NPTS;

  for (int j=t; j<4096; j+=256){ int row = j & 63, f = j >> 6; rowf[row*68+f] = xb[(size_t)f*NPTS + n0 + row]; }
  if (t < 64) rowsq[t] = sqb[n0 + t];
  __syncthreads();

  const int cl = l & 15;
  const int rl = l >> 4;
  float rsq[4]; int nself[4];
  #pragma unroll
  for (int jr=0;jr<4;++jr){ int r = w*16 + rl*4 + jr; rsq[jr] = rowsq[r]; nself[jr] = n0 + r; }

  float val[16]; int idx[16];
  #pragma unroll
  for (int q=0;q<16;++q){ val[q] = FINF; idx[q] = 0; }
  const int selrow = w*16 + (l>>2);
  const int selc   = l & 3;
  const int Xs     = (8*((l>>4)&3)) ^ (4*((l>>2)&3));   // dtile row-XOR for sel lane
  const int sbase  = selrow*64 + selc;

  // chunk-invariant xv byte offsets: addr = xt + off[i] + jc*256
  int off[16];
  #pragma unroll
  for (int i=0;i<16;++i) off[i] = cl*1024 + 16*(i^cl);

  for (int cc=0; cc<2048; cc+=64){
    const int c0 = cbase + cc;
    __syncthreads();                           // everyone done selecting from xt(dtile) of prev chunk
    #pragma unroll
    for (int it=0; it<4; ++it){                // stage 64f x 64c, pre-swizzled
      int i4 = it*256 + t;
      int f  = i4 >> 4;
      int c4 = (i4 & 15) << 2;
      float4 v = *(const float4*)(xb + (size_t)f*NPTS + c0 + c4);
      int fp = f ^ c4;
      xt[(c4+0)*64 + fp] = v.x;
      xt[(c4+1)*64 + fp] = v.y;
      xt[(c4+2)*64 + fp] = v.z;
      xt[(c4+3)*64 + fp] = v.w;
    }
    float csq[4];
    #pragma unroll
    for (int jc=0;jc<4;++jc) csq[jc] = sqb[c0 + cl*4 + jc];
    __syncthreads();                           // xt ready

    float acc[4][4];
    #pragma unroll
    for (int jc=0;jc<4;++jc){
      #pragma unroll
      for (int jr=0;jr<4;++jr) acc[jc][jr]=0.f;
    }
    #pragma unroll
    for (int i=0;i<16;++i){
      float4 xv[4], rf[4];
      #pragma unroll
      for (int jc=0;jc<4;++jc) xv[jc] = *(const float4*)((const char*)xt + off[i] + jc*256);
      #pragma unroll
      for (int jr=0;jr<4;++jr) rf[jr] = *(const float4*)&rowf[(w*16+rl*4+jr)*68 + i*4];
      #pragma unroll
      for (int jc=0;jc<4;++jc){
        #pragma unroll
        for (int jr=0;jr<4;++jr){
          acc[jc][jr] = fmaf(xv[jc].x, rf[jr].x, acc[jc][jr]);
          acc[jc][jr] = fmaf(xv[jc].y, rf[jr].y, acc[jc][jr]);
          acc[jc][jr] = fmaf(xv[jc].z, rf[jr].z, acc[jc][jr]);
          acc[jc][jr] = fmaf(xv[jc].w, rf[jr].w, acc[jc][jr]);
        }
      }
    }

    // d = rsq + csq - 2*dot into registers (before barrier), self-exclusion per element
    float4 dres[4];
    #pragma unroll
    for (int jr=0;jr<4;++jr){
      const int c = c0 + cl*4;
      float4 dd;
      dd.x = fmaf(-2.f, acc[0][jr], rsq[jr] + csq[0]); if (c+0 == nself[jr]) dd.x = FINF;
      dd.y = fmaf(-2.f, acc[1][jr], rsq[jr] + csq[1]); if (c+1 == nself[jr]) dd.y = FINF;
      dd.z = fmaf(-2.f, acc[2][jr], rsq[jr] + csq[2]); if (c+2 == nself[jr]) dd.z = FINF;
      dd.w = fmaf(-2.f, acc[3][jr], rsq[jr] + csq[3]); if (c+3 == nself[jr]) dd.w = FINF;
      dres[jr] = dd;
    }
    __syncthreads();                           // all waves done reading xt -> safe to overwrite as dtile
    #pragma unroll
    for (int jr=0;jr<4;++jr){                  // b128 dtile write, phys col = 4cl ^ (8rl ^ 4jr)
      const int row = w*16 + rl*4 + jr;
      const int X   = (8*rl) ^ (4*jr);
      *(float4*)&xt[row*64 + ((cl*4) ^ X)] = dres[jr];
    }
    // two-phase selection (wave-local rows; LDS deps handled by compiler lgkmcnt)
    {
      const float thr = val[15];
      unsigned mask = 0;
      #pragma unroll
      for (int j=15;j>=0;--j){
        const float d = xt[sbase + ((4*j) ^ Xs)];
        mask = (mask << 1) | (d < thr ? 1u : 0u);
      }
      while (mask){
        const int j = __builtin_ctz(mask);
        mask &= mask - 1;
        const float d = xt[sbase + ((4*j) ^ Xs)];
        if (d < val[15]){
          val[15] = d; idx[15] = c0 + selc + 4*j;
          #pragma unroll
          for (int q=15;q>0;--q){
            const bool s_ = val[q] < val[q-1];
            const float tv = val[q], tu = val[q-1];
            val[q]   = s_ ? tu : tv;
            val[q-1] = s_ ? tv : tu;
            const int iv = idx[q], iu = idx[q-1];
            idx[q]   = s_ ? iu : iv;
            idx[q-1] = s_ ? iv : iu;
          }
        }
      }
    }
  }

  // merge 4 sorted per-lane lists -> sorted global top-16 of this half
  float myv[4]; int myi[4];
  #pragma unroll
  for (int round=0; round<16; ++round){
    float v = val[0]; int ii = idx[0]; int src = selc;
    #pragma unroll
    for (int mm=1; mm<4; mm<<=1){
      const float ov = __shfl_xor(v, mm);
      const int   oi = __shfl_xor(ii, mm);
      const int   os = __shfl_xor(src, mm);
      const bool take = (ov < v) || (ov == v && os < src);
      v = take ? ov : v; ii = take ? oi : ii; src = take ? os : src;
    }
    if (selc == src){
      #pragma unroll
      for (int q=0;q<15;++q){ val[q]=val[q+1]; idx[q]=idx[q+1]; }
      val[15] = FINF;
    }
    if ((round & 3) == selc){ myv[round>>2] = v; myi[round>>2] = ii; }
  }
  {
    const int bn = b*NPTS + n0 + selrow;
    float2* pp = pairs + (size_t)bn*32 + z*16;
    #pragma unroll
    for (int q=0;q<4;++q) pp[q*4 + selc] = make_float2(myv[q], __int_as_float(myi[q]));
  }
}

// ---------------- merge two sorted 16-lists per row -> final 16 neighbor indices ----------------
__global__ __launch_bounds__(256) void kmerge_kernel(const float2* __restrict__ pairs, int* __restrict__ idxout){
  const int bn = blockIdx.x*256 + threadIdx.x;
  const float2* p = pairs + (size_t)bn*32;
  float val[16]; int idx[16];
  #pragma unroll
  for (int q=0;q<16;++q){ float2 e = p[q]; val[q] = e.x; idx[q] = __float_as_int(e.y); }
  #pragma unroll
  for (int j=16;j<32;++j){
    float2 e = p[j];
    if (e.x < val[15]){
      val[15] = e.x; idx[15] = __float_as_int(e.y);
      #pragma unroll
      for (int q=15;q>0;--q){
        const bool s_ = val[q] < val[q-1];
        const float tv = val[q], tu = val[q-1];
        val[q] = s_?tu:tv; val[q-1] = s_?tv:tu;
        const int iv = idx[q], iu = idx[q-1];
        idx[q] = s_?iu:iv; idx[q-1] = s_?iv:iu;
      }
    }
  }
  int* op = idxout + (size_t)bn*KNB;
  #pragma unroll
  for (int q=0;q<KNB;++q) op[q] = idx[q];
}

// ---------------- gather V at neighbors: sel=Ubar+(gamma>=0?max:min), channel stats ----------------
__global__ __launch_bounds__(256) void gather_kernel(const float* __restrict__ vt, const float* __restrict__ ubar,
                                                     const int* __restrict__ idxnb, const float* __restrict__ gamma,
                                                     float* __restrict__ outsel, float* __restrict__ gsum,
                                                     float* __restrict__ gsumsq){
  const int t = threadIdx.x;
  const int o = t & 127;
  const int h = __builtin_amdgcn_readfirstlane(t >> 7);   // wave-uniform point half
  const int b = blockIdx.x & 7;                           // batch -> XCD: vt[b]=2MB L2-resident
  const int nblk = (blockIdx.x >> 3) * 64;
  const float gam = gamma[o];
  const float* vtb = vt + (size_t)b*NPTS*FOUT + o;
  float bs = 0.f, bsq = 0.f;
  for (int p=0; p<8; ++p){
    const int ng = nblk + (h*8 + p)*4;
    float selv[4];
    #pragma unroll
    for (int j=0; j<4; ++j){
      const int n  = ng + j;
      const int bn = b*NPTS + n;
      const int* ip = idxnb + (size_t)bn*KNB;             // wave-uniform -> s_load
      float mx = -FINF, mn = FINF, s1 = 0.f, s2 = 0.f;
      #pragma unroll
      for (int kk=0; kk<KNB; ++kk){
        const int m = ip[kk];
        const float v = vtb[(size_t)m*FOUT];              // 256B coalesced per neighbor
        mx = fmaxf(mx, v); mn = fminf(mn, v); s1 += v; s2 = fmaf(v, v, s2);
      }
      const float c = ubar[(size_t)bn*FOUT + o];
      selv[j] = c + (gam >= 0.f ? mx : mn);
      bs  += fmaf(16.f, c, s1);                           // sum_k y = 16c + S1
      bsq += fmaf(16.f*c, c, fmaf(2.f*c, s1, s2));        // sum_k y^2 = 16c^2 + 2c S1 + S2
    }
    *(float4*)&outsel[((size_t)b*FOUT + o)*NPTS + ng] = make_float4(selv[0],selv[1],selv[2],selv[3]);
  }
  atomicAdd(&gsum[o], bs);
  atomicAdd(&gsumsq[o], bsq);
}

// ---------------- BN stats -> per-channel affine a,c ----------------
__global__ void stats_kernel(const float* __restrict__ gsum, const float* __restrict__ gsumsq,
                             const float* __restrict__ gamma, const float* __restrict__ beta,
                             float* __restrict__ ac){
  const int o = threadIdx.x;
  const float invM = 1.f / (float)(BATCH*NPTS*KNB);
  const float mean = gsum[o] * invM;
  const float var  = gsumsq[o] * invM - mean*mean;
  const float r = rsqrtf(var + BN_EPS);
  const float a = gamma[o] * r;
  ac[o] = a;
  ac[FOUT+o] = beta[o] - mean * a;
}

// ---------------- in-place relu(a*y+c) on d_out ----------------
__global__ __launch_bounds__(256) void apply_kernel(float* __restrict__ out, const float* __restrict__ ac){
  const int i4 = blockIdx.x*256 + threadIdx.x;
  const int o = (i4 >> 10) & 127;
  const float a = ac[o], c = ac[FOUT+o];
  float4* p = (float4*)out;
  float4 v = p[i4];
  v.x = fmaxf(fmaf(a, v.x, c), 0.f);
  v.y = fmaxf(fmaf(a, v.y, c), 0.f);
  v.z = fmaxf(fmaf(a, v.z, c), 0.f);
  v.w = fmaxf(fmaf(a, v.w, c), 0.f);
  p[i4] = v;
}

extern "C" void kernel_launch(void* const* d_in, const int* in_sizes, int n_in,
                              void* d_out, int out_size, void* d_ws, size_t ws_size,
                              hipStream_t stream){
  const float* x     = (const float*)d_in[0];
  const float* W     = (const float*)d_in[1];
  const float* bias  = (const float*)d_in[2];
  const float* gamma = (const float*)d_in[3];
  const float* beta  = (const float*)d_in[4];
  char* ws = (char*)d_ws;
  float*  sq     = (float*)(ws + OFF_SQ);
  int*    idxnb  = (int*)(ws + OFF_IDX);
  float2* pairs  = (float2*)(ws + OFF_PAIRS);
  float*  ubar   = (float*)(ws + OFF_UBAR);
  float*  vt     = (float*)(ws + OFF_VT);
  float*  gsum   = (float*)(ws + OFF_GSUM);
  float*  gsumsq = (float*)(ws + OFF_GSUMSQ);
  float*  ac     = (float*)(ws + OFF_AC);
  float*  out    = (float*)d_out;

  hipMemsetAsync(ws + OFF_GSUM, 0, 2*FOUT*4, stream);
  uvsq_kernel  <<<BATCH*NPTS/64, 256, 0, stream>>>(x, W, bias, ubar, vt, sq);
  knn_kernel   <<<BATCH*(NPTS/64)*2, 256, 0, stream>>>(x, sq, pairs);
  kmerge_kernel<<<BATCH*NPTS/256, 256, 0, stream>>>(pairs, idxnb);
  gather_kernel<<<BATCH*(NPTS/64), 256, 0, stream>>>(vt, ubar, idxnb, gamma, out, gsum, gsumsq);
  stats_kernel <<<1, FOUT, 0, stream>>>(gsum, gsumsq, gamma, beta, ac);
  apply_kernel <<<BATCH*FOUT*NPTS/1024, 256, 0, stream>>>(out, ac);
}

// Round 6
// 713.417 us; speedup vs baseline: 12.3267x; 1.0665x over previous
//
#include <hip/hip_runtime.h>

#define NPTS 4096
#define FIN  64
#define FOUT 128
#define KNB  16
#define BATCH 8
#define BN_EPS 1e-5f
#define FINF 1e30f

// ---------------- ws layout (bytes) ----------------
#define OFF_SQ     (0)
#define OFF_IDX    (OFF_SQ + BATCH*NPTS*4)
#define OFF_UBAR   (OFF_IDX + BATCH*NPTS*KNB*4)
#define OFF_VT     (OFF_UBAR + BATCH*NPTS*FOUT*4)
#define OFF_GSUM   (OFF_VT + BATCH*NPTS*FOUT*4)
#define OFF_GSUMSQ (OFF_GSUM + FOUT*4)
#define OFF_AC     (OFF_GSUMSQ + FOUT*4)

// ---------------- fused: sq = sum_f x^2 ; Ubar = (W1-W2)x + b ; Vt = W2 x ----------------
__global__ __launch_bounds__(256) void uvsq_kernel(const float* __restrict__ x, const float* __restrict__ W,
                                                   const float* __restrict__ bias,
                                                   float* __restrict__ ubar, float* __restrict__ vt,
                                                   float* __restrict__ sqout){
  const int t = threadIdx.x, l = t & 63;
  const int w = __builtin_amdgcn_readfirstlane(t >> 6);   // wave-uniform -> W via s_load
  const int bid = blockIdx.x;
  const int b = bid & 7, grp = bid >> 3;                  // batch -> XCD round-robin
  const int n = grp*64 + l;
  const float* xp = x + (size_t)b*FIN*NPTS + n;
  float xc[FIN];
  float s = 0.f;
  #pragma unroll
  for (int f=0; f<FIN; ++f){ xc[f] = xp[(size_t)f*NPTS]; s = fmaf(xc[f], xc[f], s); }
  const size_t bn = (size_t)b*NPTS + n;
  if (w == 0) sqout[bn] = s;
  float* up = ubar + bn*FOUT;
  float* vp = vt   + bn*FOUT;
  for (int o = w*32; o < w*32+32; ++o){
    const float* wr = W + o*2*FIN;
    float a1=0.f, a2=0.f;
    #pragma unroll
    for (int f=0; f<FIN; ++f){ a1 = fmaf(wr[f], xc[f], a1); a2 = fmaf(wr[FIN+f], xc[f], a2); }
    up[o] = a1 - a2 + bias[o];
    vp[o] = a2;
  }
}

// ---------------- fused distances + top-16, full 4096 sweep, dbuf + 1 barrier/chunk ----------------
// r2-proven 4x4 tile + two-phase selection, restructured:
//  - xt double-buffered (2x16KB): per chunk {barrier; stage regs->buf^1; prefetch c+2; compute on buf}
//    -> ONE barrier/chunk; staging + HBM/L2 latency fully overlap compute.
//  - no z-split: grid 512 = exactly 2 blocks/CU (LDS 67.8KB), one 4096-cand stream per row
//    (40% fewer insertions than 2x2048), no kmerge, direct idx write.
//  - dtile/selection wave-private (rows w*16..+16) -> no extra barrier.
__global__ __launch_bounds__(256,2) void knn_kernel(const float* __restrict__ x, const float* __restrict__ sq,
                                                    int* __restrict__ idxout){
  __shared__ float xt[2*64*64];   // double-buffered swizzled cand features
  __shared__ float rowf[64*68];   // [row][f] stride 68 (rf broadcast reads 2-way = free)
  __shared__ float dtile[64*68];  // [row][cand] stride 68 (sel reads conflict-free)
  __shared__ float rowsq[64];
  const int t = threadIdx.x;
  const int w = t >> 6;
  const int l = t & 63;
  const int b  = blockIdx.x & 7;       // batch -> XCD (x[b] = 1MB, L2-resident)
  const int n0 = (blockIdx.x >> 3) * 64;
  const float* xb  = x  + (size_t)b*FIN*NPTS;
  const float* sqb = sq + b*NPTS;

  // stage row features + rowsq
  for (int j=t; j<4096; j+=256){ int row = j & 63, f = j >> 6; rowf[row*68+f] = xb[(size_t)f*NPTS + n0 + row]; }
  if (t < 64) rowsq[t] = sqb[n0 + t];

  // staging thread constants: thread owns cand group c4 (4 cands), f = it*16 + tf
  const int c4 = (t & 15) << 2;
  const int tf = t >> 4;

  // prologue: load + stage chunk 0 into buf 0, then load chunk 1 into regs
  float4 pre[4];
  #pragma unroll
  for (int it=0; it<4; ++it) pre[it] = *(const float4*)(xb + (size_t)(it*16 + tf)*NPTS + c4);
  #pragma unroll
  for (int it=0; it<4; ++it){
    const int f = it*16 + tf;
    const float4 v = pre[it];
    xt[(c4+0)*64 + (f ^ c4)] = v.x;
    xt[(c4+1)*64 + (f ^ c4)] = v.y;
    xt[(c4+2)*64 + (f ^ c4)] = v.z;
    xt[(c4+3)*64 + (f ^ c4)] = v.w;
  }
  #pragma unroll
  for (int it=0; it<4; ++it) pre[it] = *(const float4*)(xb + (size_t)(it*16 + tf)*NPTS + 64 + c4);

  __syncthreads();                      // rowf, rowsq, xt[0] ready

  const int cl = l & 15;
  const int rl = l >> 4;
  float rsq[4]; int nself[4];
  #pragma unroll
  for (int jr=0;jr<4;++jr){ int r = w*16 + rl*4 + jr; rsq[jr] = rowsq[r]; nself[jr] = n0 + r; }

  float val[16]; int idx[16];
  #pragma unroll
  for (int q=0;q<16;++q){ val[q] = FINF; idx[q] = 0; }
  const int selrow = w*16 + (l>>2);
  const int selc   = l & 3;
  const int sbase  = selrow*68 + selc;

  for (int c0=0; c0<NPTS; c0+=64){
    const int cur = (c0 >> 6) & 1;
    __syncthreads();                    // all waves done computing chunk c-1 (buf cur^1)
    { // stage chunk c+1 (in regs) -> buf cur^1
      float* dst = xt + ((cur^1) << 12);
      #pragma unroll
      for (int it=0; it<4; ++it){
        const int f = it*16 + tf;
        const float4 v = pre[it];
        dst[(c4+0)*64 + (f ^ c4)] = v.x;
        dst[(c4+1)*64 + (f ^ c4)] = v.y;
        dst[(c4+2)*64 + (f ^ c4)] = v.z;
        dst[(c4+3)*64 + (f ^ c4)] = v.w;
      }
    }
    { // prefetch chunk c+2 (wrap: benign valid reads)
      const int cn = (c0 + 128) & (NPTS-1);
      #pragma unroll
      for (int it=0; it<4; ++it) pre[it] = *(const float4*)(xb + (size_t)(it*16 + tf)*NPTS + cn + c4);
    }
    float csq[4];
    #pragma unroll
    for (int jc=0;jc<4;++jc) csq[jc] = sqb[c0 + cl*4 + jc];

    const float* xtc = xt + (cur << 12);
    float acc[4][4];
    #pragma unroll
    for (int jc=0;jc<4;++jc){
      #pragma unroll
      for (int jr=0;jr<4;++jr) acc[jc][jr]=0.f;
    }
    #pragma unroll
    for (int i=0;i<16;++i){             // logical f4 = 4i; physical = 4(i^cl)
      const int fp = ((i ^ cl) << 2);
      float4 xv[4], rf[4];
      #pragma unroll
      for (int jc=0;jc<4;++jc) xv[jc] = *(const float4*)&xtc[(cl*4+jc)*64 + fp];
      #pragma unroll
      for (int jr=0;jr<4;++jr) rf[jr] = *(const float4*)&rowf[(w*16+rl*4+jr)*68 + i*4];
      #pragma unroll
      for (int jc=0;jc<4;++jc){
        #pragma unroll
        for (int jr=0;jr<4;++jr){
          acc[jc][jr] = fmaf(xv[jc].x, rf[jr].x, acc[jc][jr]);
          acc[jc][jr] = fmaf(xv[jc].y, rf[jr].y, acc[jc][jr]);
          acc[jc][jr] = fmaf(xv[jc].z, rf[jr].z, acc[jc][jr]);
          acc[jc][jr] = fmaf(xv[jc].w, rf[jr].w, acc[jc][jr]);
        }
      }
    }

    // d = rsq + csq - 2*dot, b128 dtile write; self-exclusion only in diagonal chunk
    #pragma unroll
    for (int jr=0;jr<4;++jr){
      float4 dd;
      dd.x = fmaf(-2.f, acc[0][jr], rsq[jr] + csq[0]);
      dd.y = fmaf(-2.f, acc[1][jr], rsq[jr] + csq[1]);
      dd.z = fmaf(-2.f, acc[2][jr], rsq[jr] + csq[2]);
      dd.w = fmaf(-2.f, acc[3][jr], rsq[jr] + csq[3]);
      if (c0 == n0){
        const int c = c0 + cl*4;
        if (c+0 == nself[jr]) dd.x = FINF;
        if (c+1 == nself[jr]) dd.y = FINF;
        if (c+2 == nself[jr]) dd.z = FINF;
        if (c+3 == nself[jr]) dd.w = FINF;
      }
      *(float4*)&dtile[(w*16 + rl*4 + jr)*68 + cl*4] = dd;
    }
    // two-phase selection (wave-private rows; intra-wave LDS deps via lgkmcnt)
    {
      const float thr = val[15];
      unsigned mask = 0;
      #pragma unroll
      for (int j=15;j>=0;--j){
        const float d = dtile[sbase + 4*j];
        mask = (mask << 1) | (d < thr ? 1u : 0u);
      }
      while (mask){
        const int j = __builtin_ctz(mask);
        mask &= mask - 1;
        const float d = dtile[sbase + 4*j];
        if (d < val[15]){
          val[15] = d; idx[15] = c0 + selc + 4*j;
          #pragma unroll
          for (int q=15;q>0;--q){
            const bool s_ = val[q] < val[q-1];
            const float tv = val[q], tu = val[q-1];
            val[q]   = s_ ? tu : tv;
            val[q-1] = s_ ? tv : tu;
            const int iv = idx[q], iu = idx[q-1];
            idx[q]   = s_ ? iu : iv;
            idx[q-1] = s_ ? iv : iu;
          }
        }
      }
    }
  }

  // merge 4 sorted per-lane lists -> final top-16 per row, write indices
  int myidx[4];
  #pragma unroll
  for (int round=0; round<16; ++round){
    float v = val[0]; int ii = idx[0]; int src = selc;
    #pragma unroll
    for (int mm=1; mm<4; mm<<=1){
      const float ov = __shfl_xor(v, mm);
      const int   oi = __shfl_xor(ii, mm);
      const int   os = __shfl_xor(src, mm);
      const bool take = (ov < v) || (ov == v && os < src);
      v = take ? ov : v; ii = take ? oi : ii; src = take ? os : src;
    }
    if (selc == src){
      #pragma unroll
      for (int q=0;q<15;++q){ val[q]=val[q+1]; idx[q]=idx[q+1]; }
      val[15] = FINF;
    }
    if ((round & 3) == selc) myidx[round>>2] = ii;
  }
  {
    const int bn = b*NPTS + n0 + selrow;
    int* op = idxout + (size_t)bn*KNB;
    #pragma unroll
    for (int q=0;q<4;++q) op[q*4 + selc] = myidx[q];
  }
}

// ---------------- gather V at neighbors: sel=Ubar+(gamma>=0?max:min), channel stats ----------------
__global__ __launch_bounds__(256) void gather_kernel(const float* __restrict__ vt, const float* __restrict__ ubar,
                                                     const int* __restrict__ idxnb, const float* __restrict__ gamma,
                                                     float* __restrict__ outsel, float* __restrict__ gsum,
                                                     float* __restrict__ gsumsq){
  const int t = threadIdx.x;
  const int o = t & 127;
  const int h = __builtin_amdgcn_readfirstlane(t >> 7);   // wave-uniform point half
  const int b = blockIdx.x & 7;                           // batch -> XCD: vt[b]=2MB L2-resident
  const int nblk = (blockIdx.x >> 3) * 64;
  const float gam = gamma[o];
  const float* vtb = vt + (size_t)b*NPTS*FOUT + o;
  float bs = 0.f, bsq = 0.f;
  for (int p=0; p<8; ++p){
    const int ng = nblk + (h*8 + p)*4;
    float selv[4];
    #pragma unroll
    for (int j=0; j<4; ++j){
      const int n  = ng + j;
      const int bn = b*NPTS + n;
      const int* ip = idxnb + (size_t)bn*KNB;             // wave-uniform -> s_load
      float mx = -FINF, mn = FINF, s1 = 0.f, s2 = 0.f;
      #pragma unroll
      for (int kk=0; kk<KNB; ++kk){
        const int m = ip[kk];
        const float v = vtb[(size_t)m*FOUT];              // 256B coalesced per neighbor
        mx = fmaxf(mx, v); mn = fminf(mn, v); s1 += v; s2 = fmaf(v, v, s2);
      }
      const float c = ubar[(size_t)bn*FOUT + o];
      selv[j] = c + (gam >= 0.f ? mx : mn);
      bs  += fmaf(16.f, c, s1);                           // sum_k y = 16c + S1
      bsq += fmaf(16.f*c, c, fmaf(2.f*c, s1, s2));        // sum_k y^2 = 16c^2 + 2c S1 + S2
    }
    *(float4*)&outsel[((size_t)b*FOUT + o)*NPTS + ng] = make_float4(selv[0],selv[1],selv[2],selv[3]);
  }
  atomicAdd(&gsum[o], bs);
  atomicAdd(&gsumsq[o], bsq);
}

// ---------------- BN stats -> per-channel affine a,c ----------------
__global__ void stats_kernel(const float* __restrict__ gsum, const float* __restrict__ gsumsq,
                             const float* __restrict__ gamma, const float* __restrict__ beta,
                             float* __restrict__ ac){
  const int o = threadIdx.x;
  const float invM = 1.f / (float)(BATCH*NPTS*KNB);
  const float mean = gsum[o] * invM;
  const float var  = gsumsq[o] * invM - mean*mean;
  const float r = rsqrtf(var + BN_EPS);
  const float a = gamma[o] * r;
  ac[o] = a;
  ac[FOUT+o] = beta[o] - mean * a;
}

// ---------------- in-place relu(a*y+c) on d_out ----------------
__global__ __launch_bounds__(256) void apply_kernel(float* __restrict__ out, const float* __restrict__ ac){
  const int i4 = blockIdx.x*256 + threadIdx.x;
  const int o = (i4 >> 10) & 127;
  const float a = ac[o], c = ac[FOUT+o];
  float4* p = (float4*)out;
  float4 v = p[i4];
  v.x = fmaxf(fmaf(a, v.x, c), 0.f);
  v.y = fmaxf(fmaf(a, v.y, c), 0.f);
  v.z = fmaxf(fmaf(a, v.z, c), 0.f);
  v.w = fmaxf(fmaf(a, v.w, c), 0.f);
  p[i4] = v;
}

extern "C" void kernel_launch(void* const* d_in, const int* in_sizes, int n_in,
                              void* d_out, int out_size, void* d_ws, size_t ws_size,
                              hipStream_t stream){
  const float* x     = (const float*)d_in[0];
  const float* W     = (const float*)d_in[1];
  const float* bias  = (const float*)d_in[2];
  const float* gamma = (const float*)d_in[3];
  const float* beta  = (const float*)d_in[4];
  char* ws = (char*)d_ws;
  float* sq     = (float*)(ws + OFF_SQ);
  int*   idxnb  = (int*)(ws + OFF_IDX);
  float* ubar   = (float*)(ws + OFF_UBAR);
  float* vt     = (float*)(ws + OFF_VT);
  float* gsum   = (float*)(ws + OFF_GSUM);
  float* gsumsq = (float*)(ws + OFF_GSUMSQ);
  float* ac     = (float*)(ws + OFF_AC);
  float* out    = (float*)d_out;

  hipMemsetAsync(ws + OFF_GSUM, 0, 2*FOUT*4, stream);
  uvsq_kernel  <<<BATCH*NPTS/64, 256, 0, stream>>>(x, W, bias, ubar, vt, sq);
  knn_kernel   <<<BATCH*NPTS/64, 256, 0, stream>>>(x, sq, idxnb);
  gather_kernel<<<BATCH*NPTS/64, 256, 0, stream>>>(vt, ubar, idxnb, gamma, out, gsum, gsumsq);
  stats_kernel <<<1, FOUT, 0, stream>>>(gsum, gsumsq, gamma, beta, ac);
  apply_kernel <<<BATCH*FOUT*NPTS/1024, 256, 0, stream>>>(out, ac);
}

// Round 7
// 704.333 us; speedup vs baseline: 12.4857x; 1.0129x over previous
//
#include <hip/hip_runtime.h>

#define NPTS 4096
#define FIN  64
#define FOUT 128
#define KNB  16
#define BATCH 8
#define BN_EPS 1e-5f
#define FINF 1e30f

// ---------------- ws layout (bytes) ----------------
#define OFF_SQ     (0)
#define OFF_IDX    (OFF_SQ + BATCH*NPTS*4)
#define OFF_PART   (OFF_IDX + BATCH*NPTS*KNB*4)      // [512][128] partial sum(y)
#define OFF_PART2  (OFF_PART + 512*FOUT*4)           // [512][128] partial sum(y^2)
#define OFF_UBAR   (OFF_PART2 + 512*FOUT*4)
#define OFF_VT     (OFF_UBAR + BATCH*NPTS*FOUT*4)

// ---------------- fused: sq = sum_f x^2 ; Ubar = (W1-W2)x + b ; Vt = W2 x ----------------
__global__ __launch_bounds__(256) void uvsq_kernel(const float* __restrict__ x, const float* __restrict__ W,
                                                   const float* __restrict__ bias,
                                                   float* __restrict__ ubar, float* __restrict__ vt,
                                                   float* __restrict__ sqout){
  const int t = threadIdx.x, l = t & 63;
  const int w = __builtin_amdgcn_readfirstlane(t >> 6);   // wave-uniform -> W via s_load
  const int bid = blockIdx.x;
  const int b = bid & 7, grp = bid >> 3;                  // batch -> XCD round-robin
  const int n = grp*64 + l;
  const float* xp = x + (size_t)b*FIN*NPTS + n;
  float xc[FIN];
  float s = 0.f;
  #pragma unroll
  for (int f=0; f<FIN; ++f){ xc[f] = xp[(size_t)f*NPTS]; s = fmaf(xc[f], xc[f], s); }
  const size_t bn = (size_t)b*NPTS + n;
  if (w == 0) sqout[bn] = s;
  float* up = ubar + bn*FOUT;
  float* vp = vt   + bn*FOUT;
  for (int o = w*32; o < w*32+32; ++o){
    const float* wr = W + o*2*FIN;
    float a1=0.f, a2=0.f;
    #pragma unroll
    for (int f=0; f<FIN; ++f){ a1 = fmaf(wr[f], xc[f], a1); a2 = fmaf(wr[FIN+f], xc[f], a2); }
    up[o] = a1 - a2 + bias[o];
    vp[o] = a2;
  }
}

// ---------------- fused distances + top-16, full 4096 sweep, dbuf + 1 barrier/chunk ----------------
// UNCHANGED from r6 (proven 533us): protect the baseline while the rest of the pipeline is trimmed.
__global__ __launch_bounds__(256,2) void knn_kernel(const float* __restrict__ x, const float* __restrict__ sq,
                                                    int* __restrict__ idxout){
  __shared__ float xt[2*64*64];   // double-buffered swizzled cand features
  __shared__ float rowf[64*68];   // [row][f] stride 68 (rf broadcast reads 2-way = free)
  __shared__ float dtile[64*68];  // [row][cand] stride 68 (sel reads conflict-free)
  __shared__ float rowsq[64];
  const int t = threadIdx.x;
  const int w = t >> 6;
  const int l = t & 63;
  const int b  = blockIdx.x & 7;       // batch -> XCD (x[b] = 1MB, L2-resident)
  const int n0 = (blockIdx.x >> 3) * 64;
  const float* xb  = x  + (size_t)b*FIN*NPTS;
  const float* sqb = sq + b*NPTS;

  for (int j=t; j<4096; j+=256){ int row = j & 63, f = j >> 6; rowf[row*68+f] = xb[(size_t)f*NPTS + n0 + row]; }
  if (t < 64) rowsq[t] = sqb[n0 + t];

  const int c4 = (t & 15) << 2;
  const int tf = t >> 4;

  float4 pre[4];
  #pragma unroll
  for (int it=0; it<4; ++it) pre[it] = *(const float4*)(xb + (size_t)(it*16 + tf)*NPTS + c4);
  #pragma unroll
  for (int it=0; it<4; ++it){
    const int f = it*16 + tf;
    const float4 v = pre[it];
    xt[(c4+0)*64 + (f ^ c4)] = v.x;
    xt[(c4+1)*64 + (f ^ c4)] = v.y;
    xt[(c4+2)*64 + (f ^ c4)] = v.z;
    xt[(c4+3)*64 + (f ^ c4)] = v.w;
  }
  #pragma unroll
  for (int it=0; it<4; ++it) pre[it] = *(const float4*)(xb + (size_t)(it*16 + tf)*NPTS + 64 + c4);

  __syncthreads();                      // rowf, rowsq, xt[0] ready

  const int cl = l & 15;
  const int rl = l >> 4;
  float rsq[4]; int nself[4];
  #pragma unroll
  for (int jr=0;jr<4;++jr){ int r = w*16 + rl*4 + jr; rsq[jr] = rowsq[r]; nself[jr] = n0 + r; }

  float val[16]; int idx[16];
  #pragma unroll
  for (int q=0;q<16;++q){ val[q] = FINF; idx[q] = 0; }
  const int selrow = w*16 + (l>>2);
  const int selc   = l & 3;
  const int sbase  = selrow*68 + selc;

  for (int c0=0; c0<NPTS; c0+=64){
    const int cur = (c0 >> 6) & 1;
    __syncthreads();                    // all waves done computing chunk c-1 (buf cur^1)
    { // stage chunk c+1 (in regs) -> buf cur^1
      float* dst = xt + ((cur^1) << 12);
      #pragma unroll
      for (int it=0; it<4; ++it){
        const int f = it*16 + tf;
        const float4 v = pre[it];
        dst[(c4+0)*64 + (f ^ c4)] = v.x;
        dst[(c4+1)*64 + (f ^ c4)] = v.y;
        dst[(c4+2)*64 + (f ^ c4)] = v.z;
        dst[(c4+3)*64 + (f ^ c4)] = v.w;
      }
    }
    { // prefetch chunk c+2 (wrap: benign valid reads)
      const int cn = (c0 + 128) & (NPTS-1);
      #pragma unroll
      for (int it=0; it<4; ++it) pre[it] = *(const float4*)(xb + (size_t)(it*16 + tf)*NPTS + cn + c4);
    }
    float csq[4];
    #pragma unroll
    for (int jc=0;jc<4;++jc) csq[jc] = sqb[c0 + cl*4 + jc];

    const float* xtc = xt + (cur << 12);
    float acc[4][4];
    #pragma unroll
    for (int jc=0;jc<4;++jc){
      #pragma unroll
      for (int jr=0;jr<4;++jr) acc[jc][jr]=0.f;
    }
    #pragma unroll
    for (int i=0;i<16;++i){             // logical f4 = 4i; physical = 4(i^cl)
      const int fp = ((i ^ cl) << 2);
      float4 xv[4], rf[4];
      #pragma unroll
      for (int jc=0;jc<4;++jc) xv[jc] = *(const float4*)&xtc[(cl*4+jc)*64 + fp];
      #pragma unroll
      for (int jr=0;jr<4;++jr) rf[jr] = *(const float4*)&rowf[(w*16+rl*4+jr)*68 + i*4];
      #pragma unroll
      for (int jc=0;jc<4;++jc){
        #pragma unroll
        for (int jr=0;jr<4;++jr){
          acc[jc][jr] = fmaf(xv[jc].x, rf[jr].x, acc[jc][jr]);
          acc[jc][jr] = fmaf(xv[jc].y, rf[jr].y, acc[jc][jr]);
          acc[jc][jr] = fmaf(xv[jc].z, rf[jr].z, acc[jc][jr]);
          acc[jc][jr] = fmaf(xv[jc].w, rf[jr].w, acc[jc][jr]);
        }
      }
    }

    #pragma unroll
    for (int jr=0;jr<4;++jr){
      float4 dd;
      dd.x = fmaf(-2.f, acc[0][jr], rsq[jr] + csq[0]);
      dd.y = fmaf(-2.f, acc[1][jr], rsq[jr] + csq[1]);
      dd.z = fmaf(-2.f, acc[2][jr], rsq[jr] + csq[2]);
      dd.w = fmaf(-2.f, acc[3][jr], rsq[jr] + csq[3]);
      if (c0 == n0){
        const int c = c0 + cl*4;
        if (c+0 == nself[jr]) dd.x = FINF;
        if (c+1 == nself[jr]) dd.y = FINF;
        if (c+2 == nself[jr]) dd.z = FINF;
        if (c+3 == nself[jr]) dd.w = FINF;
      }
      *(float4*)&dtile[(w*16 + rl*4 + jr)*68 + cl*4] = dd;
    }
    {
      const float thr = val[15];
      unsigned mask = 0;
      #pragma unroll
      for (int j=15;j>=0;--j){
        const float d = dtile[sbase + 4*j];
        mask = (mask << 1) | (d < thr ? 1u : 0u);
      }
      while (mask){
        const int j = __builtin_ctz(mask);
        mask &= mask - 1;
        const float d = dtile[sbase + 4*j];
        if (d < val[15]){
          val[15] = d; idx[15] = c0 + selc + 4*j;
          #pragma unroll
          for (int q=15;q>0;--q){
            const bool s_ = val[q] < val[q-1];
            const float tv = val[q], tu = val[q-1];
            val[q]   = s_ ? tu : tv;
            val[q-1] = s_ ? tv : tu;
            const int iv = idx[q], iu = idx[q-1];
            idx[q]   = s_ ? iu : iv;
            idx[q-1] = s_ ? iv : iu;
          }
        }
      }
    }
  }

  int myidx[4];
  #pragma unroll
  for (int round=0; round<16; ++round){
    float v = val[0]; int ii = idx[0]; int src = selc;
    #pragma unroll
    for (int mm=1; mm<4; mm<<=1){
      const float ov = __shfl_xor(v, mm);
      const int   oi = __shfl_xor(ii, mm);
      const int   os = __shfl_xor(src, mm);
      const bool take = (ov < v) || (ov == v && os < src);
      v = take ? ov : v; ii = take ? oi : ii; src = take ? os : src;
    }
    if (selc == src){
      #pragma unroll
      for (int q=0;q<15;++q){ val[q]=val[q+1]; idx[q]=idx[q+1]; }
      val[15] = FINF;
    }
    if ((round & 3) == selc) myidx[round>>2] = ii;
  }
  {
    const int bn = b*NPTS + n0 + selrow;
    int* op = idxout + (size_t)bn*KNB;
    #pragma unroll
    for (int q=0;q<4;++q) op[q*4 + selc] = myidx[q];
  }
}

// ---------------- gather V at neighbors: sel=Ubar+(gamma>=0?max:min), per-block partial stats ----------------
// Atomics and memset removed: block bid writes its channel partials to part/part2[bid][o].
__global__ __launch_bounds__(256) void gather_kernel(const float* __restrict__ vt, const float* __restrict__ ubar,
                                                     const int* __restrict__ idxnb, const float* __restrict__ gamma,
                                                     float* __restrict__ outsel, float* __restrict__ part,
                                                     float* __restrict__ part2){
  __shared__ float red[2*FOUT];
  const int t = threadIdx.x;
  const int o = t & 127;
  const int h = __builtin_amdgcn_readfirstlane(t >> 7);   // wave-uniform point half
  const int bid = blockIdx.x;
  const int b = bid & 7;                                  // batch -> XCD: vt[b]=2MB L2-resident
  const int nblk = (bid >> 3) * 64;
  const float gam = gamma[o];
  const float* vtb = vt + (size_t)b*NPTS*FOUT + o;
  float bs = 0.f, bsq = 0.f;
  for (int p=0; p<8; ++p){
    const int ng = nblk + (h*8 + p)*4;
    float selv[4];
    #pragma unroll
    for (int j=0; j<4; ++j){
      const int n  = ng + j;
      const int bn = b*NPTS + n;
      const int* ip = idxnb + (size_t)bn*KNB;             // wave-uniform -> s_load
      float mx = -FINF, mn = FINF, s1 = 0.f, s2 = 0.f;
      #pragma unroll
      for (int kk=0; kk<KNB; ++kk){
        const int m = ip[kk];
        const float v = vtb[(size_t)m*FOUT];              // 256B coalesced per neighbor
        mx = fmaxf(mx, v); mn = fminf(mn, v); s1 += v; s2 = fmaf(v, v, s2);
      }
      const float c = ubar[(size_t)bn*FOUT + o];
      selv[j] = c + (gam >= 0.f ? mx : mn);
      bs  += fmaf(16.f, c, s1);                           // sum_k y = 16c + S1
      bsq += fmaf(16.f*c, c, fmaf(2.f*c, s1, s2));        // sum_k y^2 = 16c^2 + 2c S1 + S2
    }
    *(float4*)&outsel[((size_t)b*FOUT + o)*NPTS + ng] = make_float4(selv[0],selv[1],selv[2],selv[3]);
  }
  if (h == 1){ red[o] = bs; red[FOUT+o] = bsq; }
  __syncthreads();
  if (h == 0){
    part [bid*FOUT + o] = bs  + red[o];
    part2[bid*FOUT + o] = bsq + red[FOUT+o];
  }
}

// ---------------- fused BN-stats + relu(a*y+c): one block per (b,o) ----------------
// Each block redundantly reduces the 512 partials of its channel (2KB, L2-hot), then
// applies the affine+relu in place on its 16KB [b][o][:] slab.
__global__ __launch_bounds__(256) void applybn_kernel(float* __restrict__ out, const float* __restrict__ part,
                                                      const float* __restrict__ part2,
                                                      const float* __restrict__ gamma, const float* __restrict__ beta){
  __shared__ float red[8];
  const int bid = blockIdx.x;          // 1024 = 8 b x 128 o
  const int o = bid & 127, b = bid >> 7;
  const int t = threadIdx.x;
  float s1 = part [t*FOUT + o] + part [(t+256)*FOUT + o];
  float s2 = part2[t*FOUT + o] + part2[(t+256)*FOUT + o];
  #pragma unroll
  for (int m=1; m<64; m<<=1){ s1 += __shfl_xor(s1, m); s2 += __shfl_xor(s2, m); }
  const int w = t >> 6, l = t & 63;
  if (l == 0){ red[w] = s1; red[4+w] = s2; }
  __syncthreads();
  s1 = red[0]+red[1]+red[2]+red[3];
  s2 = red[4]+red[5]+red[6]+red[7];
  const float invM = 1.f / (float)(BATCH*NPTS*KNB);
  const float mean = s1 * invM;
  const float var  = s2 * invM - mean*mean;
  const float a = gamma[o] * rsqrtf(var + BN_EPS);
  const float c = beta[o] - mean * a;
  float4* p = (float4*)(out + ((size_t)(b*FOUT + o))*NPTS);
  #pragma unroll
  for (int q=0; q<4; ++q){
    float4 v = p[t + q*256];
    v.x = fmaxf(fmaf(a, v.x, c), 0.f);
    v.y = fmaxf(fmaf(a, v.y, c), 0.f);
    v.z = fmaxf(fmaf(a, v.z, c), 0.f);
    v.w = fmaxf(fmaf(a, v.w, c), 0.f);
    p[t + q*256] = v;
  }
}

extern "C" void kernel_launch(void* const* d_in, const int* in_sizes, int n_in,
                              void* d_out, int out_size, void* d_ws, size_t ws_size,
                              hipStream_t stream){
  const float* x     = (const float*)d_in[0];
  const float* W     = (const float*)d_in[1];
  const float* bias  = (const float*)d_in[2];
  const float* gamma = (const float*)d_in[3];
  const float* beta  = (const float*)d_in[4];
  char* ws = (char*)d_ws;
  float* sq     = (float*)(ws + OFF_SQ);
  int*   idxnb  = (int*)(ws + OFF_IDX);
  float* part   = (float*)(ws + OFF_PART);
  float* part2  = (float*)(ws + OFF_PART2);
  float* ubar   = (float*)(ws + OFF_UBAR);
  float* vt     = (float*)(ws + OFF_VT);
  float* out    = (float*)d_out;

  uvsq_kernel   <<<BATCH*NPTS/64, 256, 0, stream>>>(x, W, bias, ubar, vt, sq);
  knn_kernel    <<<BATCH*NPTS/64, 256, 0, stream>>>(x, sq, idxnb);
  gather_kernel <<<BATCH*NPTS/64, 256, 0, stream>>>(vt, ubar, idxnb, gamma, out, part, part2);
  applybn_kernel<<<BATCH*FOUT,    256, 0, stream>>>(out, part, part2, gamma, beta);
}